// Round 8
// baseline (660.041 us; speedup 1.0000x reference)
//
#include <hip/hip_runtime.h>
#include <hip/hip_fp16.h>
#include <cmath>

#define H 128
#define GAMMA 0.1f
#define EPS 0.1f
#define NEG 0.01f
#define NGRAPH 256

typedef _Float16 half_t;
typedef _Float16 f16x8 __attribute__((ext_vector_type(8)));
typedef _Float16 f16x4 __attribute__((ext_vector_type(4)));
typedef float f32x4 __attribute__((ext_vector_type(4)));

__device__ __forceinline__ float fast_tanh(float v) {
    float e = __builtin_amdgcn_exp2f(v * 2.8853900817779268f);
    float r = __builtin_amdgcn_rcpf(e + 1.0f);
    return 1.0f - 2.0f * r;
}

// ---------------- precompute weights in MFMA B-fragment order:
// WtTf[((s*8+ct)*64+lane)*8+t] = M[j=ct*16+(lane&15)][k=s*32+(lane>>4)*8+t]
// where M[j][k] = (k<H) ? W[j][k]-W[k][j]-gamma*delta(j,k) : lin_w[j][k-H]
__global__ void prep_kernel(const float* __restrict__ W, const float* __restrict__ lin_w,
                            half_t* __restrict__ WtTf) {
    int idx = blockIdx.x * 256 + threadIdx.x;   // 32768 threads
    int t = idx & 7;
    int lane = (idx >> 3) & 63;
    int ct = (idx >> 9) & 7;
    int s = idx >> 12;
    int q = lane >> 4, m = lane & 15;
    int j = ct * 16 + m;
    int k = s * 32 + q * 8 + t;
    float v;
    if (k < H) v = W[j * H + k] - W[k * H + j] - (j == k ? GAMMA : 0.f);
    else       v = lin_w[j * H + (k - H)];
    WtTf[idx] = (half_t)v;
}

// ---------------- f32 -> f16 cast (x0 -> xh)
__global__ void cast_kernel(const float* __restrict__ x, half_t* __restrict__ xh, int n4) {
    int i = blockIdx.x * 256 + threadIdx.x;
    if (i < n4) {
        float4 v = *(const float4*)(x + (size_t)i * 4);
        half_t* o = xh + (size_t)i * 4;
        o[0] = (half_t)v.x; o[1] = (half_t)v.y; o[2] = (half_t)v.z; o[3] = (half_t)v.w;
    }
}

// ---------------- CSR build
__global__ void count_kernel(const int* __restrict__ dst, int* __restrict__ deg, int E) {
    int e = blockIdx.x * blockDim.x + threadIdx.x;
    if (e < E) atomicAdd(&deg[dst[e]], 1);
}

#define SCHUNK 2048
__global__ __launch_bounds__(256) void scan_part(const int* __restrict__ deg,
                                                 int* __restrict__ partials, int N) {
    __shared__ int red[256];
    int t = threadIdx.x, b = blockIdx.x;
    int base = b * SCHUNK + t * 8;
    int s = 0;
#pragma unroll
    for (int i = 0; i < 8; ++i) { int idx = base + i; if (idx < N) s += deg[idx]; }
    red[t] = s;
    __syncthreads();
    for (int off = 128; off > 0; off >>= 1) {
        if (t < off) red[t] += red[t + off];
        __syncthreads();
    }
    if (t == 0) partials[b] = red[0];
}

__global__ void scan_mid(const int* __restrict__ partials, int* __restrict__ blkoff, int nblk) {
    int lane = threadIdx.x;   // 64 threads
    int p = (lane < nblk) ? partials[lane] : 0;
    int v = p;
    for (int off = 1; off < 64; off <<= 1) {
        int u = __shfl_up(v, off);
        if (lane >= off) v += u;
    }
    if (lane < nblk) blkoff[lane] = v - p;
}

__global__ __launch_bounds__(256) void scan_final(const int* __restrict__ deg,
        const int* __restrict__ blkoff, int* __restrict__ row_start,
        int* __restrict__ cursor, int N, int E) {
    __shared__ int red[256];
    int t = threadIdx.x, b = blockIdx.x;
    int base = b * SCHUNK + t * 8;
    int v[8]; int s = 0;
#pragma unroll
    for (int i = 0; i < 8; ++i) { int idx = base + i; v[i] = (idx < N) ? deg[idx] : 0; s += v[i]; }
    red[t] = s;
    __syncthreads();
    for (int off = 1; off < 256; off <<= 1) {
        int u = (t >= off) ? red[t - off] : 0;
        __syncthreads();
        red[t] += u;
        __syncthreads();
    }
    int run = blkoff[b] + red[t] - s;
#pragma unroll
    for (int i = 0; i < 8; ++i) {
        int idx = base + i;
        if (idx < N) { row_start[idx] = run; cursor[idx] = run; run += v[i]; }
    }
    if (b == 0 && t == 0) row_start[N] = E;
}

__global__ void fill_kernel(const int* __restrict__ src, const int* __restrict__ dst,
                            int* __restrict__ cursor, int* __restrict__ csr_src, int E) {
    int e = blockIdx.x * blockDim.x + threadIdx.x;
    if (e < E) {
        int p = atomicAdd(&cursor[dst[e]], 1);
        csr_src[p] = src[e];
    }
}

// ---------------- FUSED per-iteration kernel: gather (to LDS) + MFMA conv + update.
// Block = 256 thr = 4 waves, 128 rows. Phase 1: wave w gathers xagg for its 32
// rows into sAgg (R4 half-layout: 32 lanes x f16x4, 2 loads in flight).
// Phase 2: MFMA over K=256 = [xh(global) | sAgg(LDS)] with fragment-ordered
// weights read coalesced from global. Epilogue: residual + eps*tanh.
// Exec-mask discipline: every __shfl executes with the full wave active.
#define CROWS 128
#define AGLD 136   // sAgg row stride (halfs): 272B -> 68 words, 68%32=4 -> 2-way free
__global__ __launch_bounds__(256) void fused_iter(
        const float* __restrict__ xin, const half_t* __restrict__ xh,
        const int* __restrict__ row_start, const int* __restrict__ csr_src,
        const half_t* __restrict__ WtTf, const float* __restrict__ bias,
        float* __restrict__ xout, half_t* __restrict__ xouth, int N, int write_h) {
    __shared__ __align__(16) half_t sAgg[CROWS * AGLD];
    int tid = threadIdx.x;
    int wave = tid >> 6, lane = tid & 63;
    int half = lane >> 5, li = lane & 31;
    int n0 = blockIdx.x * CROWS + wave * 32;

    // preload row_start[n0 .. n0+32] across lanes 0..32
    int ridx = n0 + (lane < 33 ? lane : 32);
    ridx = min(ridx, N);
    int rsl = row_start[ridx];

    for (int i = 0; i < 32; ++i) {
        int node = n0 + i;
        if (node >= N) break;                    // wave-uniform
        int begin = __shfl(rsl, i);
        int end   = __shfl(rsl, i + 1);
        float a0 = 0.f, a1 = 0.f, a2 = 0.f, a3 = 0.f;
        float b0 = 0.f, b1 = 0.f, b2 = 0.f, b3 = 0.f;
        for (int base = begin; base < end; base += 64) {
            int cnt = min(64, end - base);
            int myidx = (lane < cnt) ? csr_src[base + lane] : 0;
            int j = 0;
            for (; j + 3 < cnt; j += 4) {        // 2 independent loads in flight
                int s0 = __shfl(myidx, j + half);
                int s1 = __shfl(myidx, j + 2 + half);
                f16x4 v0 = *(const f16x4*)(xh + (size_t)s0 * H + li * 4);
                f16x4 v1 = *(const f16x4*)(xh + (size_t)s1 * H + li * 4);
                a0 += (float)v0[0]; a1 += (float)v0[1]; a2 += (float)v0[2]; a3 += (float)v0[3];
                b0 += (float)v1[0]; b1 += (float)v1[1]; b2 += (float)v1[2]; b3 += (float)v1[3];
            }
            int rem = cnt - j;                   // 0..3, wave-uniform
            if (rem > 0) {                       // uniform: all lanes shfl
                int take = rem < 2 ? rem : 2;
                int sel = j + (half < take ? half : 0);
                int s0 = __shfl(myidx, sel);
                f16x4 v0 = *(const f16x4*)(xh + (size_t)s0 * H + li * 4);
                if (half < take) {
                    a0 += (float)v0[0]; a1 += (float)v0[1]; a2 += (float)v0[2]; a3 += (float)v0[3];
                }
                j += take; rem -= take;
            }
            if (rem > 0) {                       // rem was 3: one last edge
                int s0 = __shfl(myidx, j);
                f16x4 v0 = *(const f16x4*)(xh + (size_t)s0 * H + li * 4);
                if (half == 0) {
                    b0 += (float)v0[0]; b1 += (float)v0[1]; b2 += (float)v0[2]; b3 += (float)v0[3];
                }
            }
        }
        a0 += b0; a1 += b1; a2 += b2; a3 += b3;
        a0 += __shfl_xor(a0, 32); a1 += __shfl_xor(a1, 32);
        a2 += __shfl_xor(a2, 32); a3 += __shfl_xor(a3, 32);
        if (half == 0) {
            f16x4 o; o[0] = (half_t)a0; o[1] = (half_t)a1; o[2] = (half_t)a2; o[3] = (half_t)a3;
            *(f16x4*)&sAgg[(wave * 32 + i) * AGLD + li * 4] = o;
        }
    }
    __syncthreads();

    // Phase 2: MFMA
    int q = lane >> 4, m = lane & 15;
    f32x4 acc[2][8];
#pragma unroll
    for (int rt = 0; rt < 2; ++rt)
#pragma unroll
        for (int ct = 0; ct < 8; ++ct) acc[rt][ct] = (f32x4){0.f, 0.f, 0.f, 0.f};

#pragma unroll
    for (int s = 0; s < 8; ++s) {
        f16x8 afrag[2];
#pragma unroll
        for (int rt = 0; rt < 2; ++rt) {
            if (s < 4) {
                int row = min(n0 + rt * 16 + m, N - 1);
                afrag[rt] = *(const f16x8*)(xh + (size_t)row * H + s * 32 + q * 8);
            } else {
                afrag[rt] = *(const f16x8*)&sAgg[(wave * 32 + rt * 16 + m) * AGLD
                                                 + (s - 4) * 32 + q * 8];
            }
        }
#pragma unroll
        for (int ct = 0; ct < 8; ++ct) {
            f16x8 bfrag = *(const f16x8*)(WtTf + ((s * 8 + ct) * 64 + lane) * 8);
            acc[0][ct] = __builtin_amdgcn_mfma_f32_16x16x32_f16(afrag[0], bfrag, acc[0][ct], 0, 0, 0);
            acc[1][ct] = __builtin_amdgcn_mfma_f32_16x16x32_f16(afrag[1], bfrag, acc[1][ct], 0, 0, 0);
        }
    }

#pragma unroll
    for (int rt = 0; rt < 2; ++rt) {
#pragma unroll
        for (int r = 0; r < 4; ++r) {
            int row = n0 + rt * 16 + q * 4 + r;
            if (row < N) {
#pragma unroll
                for (int ct = 0; ct < 8; ++ct) {
                    int col = ct * 16 + m;
                    float c = acc[rt][ct][r] + bias[col];
                    float o = xin[(size_t)row * H + col] + EPS * fast_tanh(c);
                    xout[(size_t)row * H + col] = o;
                    if (write_h) xouth[(size_t)row * H + col] = (half_t)o;
                }
            }
        }
    }
}

// ---------------- fused triple pooling + 2-layer MLP (one block per graph)
__global__ __launch_bounds__(1024) void pool_mlp(const float* __restrict__ x,
        const int* __restrict__ batch,
        const float* __restrict__ l1_w, const float* __restrict__ l1_b,
        const float* __restrict__ l2_w, const float* __restrict__ l2_b,
        float* __restrict__ out, int N) {
    __shared__ float ssum[8][128];
    __shared__ float smax[8][128];
    __shared__ __align__(16) float sp[384];
    __shared__ __align__(16) float sh[192];
    int g = blockIdx.x, t = threadIdx.x;
    int feat = t & 127, slot = t >> 7;   // 8 slots
    int lo = 0, hi = N;
    while (lo < hi) { int mid = (lo + hi) >> 1; if (batch[mid] < g) lo = mid + 1; else hi = mid; }
    int start = lo;
    hi = N;
    while (lo < hi) { int mid = (lo + hi) >> 1; if (batch[mid] < g + 1) lo = mid + 1; else hi = mid; }
    int end = lo;
    float sum = 0.f, mx = -INFINITY;
    for (int n = start + slot; n < end; n += 8) {
        float v = x[(size_t)n * H + feat];
        sum += v;
        mx = fmaxf(mx, v);
    }
    ssum[slot][feat] = sum;
    smax[slot][feat] = mx;
    __syncthreads();
    if (t < 128) {
        float s = 0.f, m = -INFINITY;
#pragma unroll
        for (int k = 0; k < 8; ++k) { s += ssum[k][t]; m = fmaxf(m, smax[k][t]); }
        int cnt = end - start;
        sp[t] = s;
        sp[128 + t] = (cnt > 0) ? m : 0.f;
        sp[256 + t] = s / (float)(cnt > 0 ? cnt : 1);
    }
    __syncthreads();
    if (t < 192) {
        float acc = l1_b[t];
        const float* wr = l1_w + (size_t)t * 384;
        for (int k = 0; k < 384; k += 4) {
            float4 w = *(const float4*)(wr + k);
            float4 p = *(const float4*)(sp + k);
            acc += w.x * p.x + w.y * p.y + w.z * p.z + w.w * p.w;
        }
        sh[t] = acc > 0.f ? acc : NEG * acc;
    }
    __syncthreads();
    if (t < 64) {
        float acc = l2_b[t];
        const float* wr = l2_w + (size_t)t * 192;
        for (int k = 0; k < 192; k += 4) {
            float4 w = *(const float4*)(wr + k);
            float4 p = *(const float4*)(sh + k);
            acc += w.x * p.x + w.y * p.y + w.z * p.z + w.w * p.w;
        }
        out[g * 64 + t] = acc > 0.f ? acc : NEG * acc;
    }
}

extern "C" void kernel_launch(void* const* d_in, const int* in_sizes, int n_in,
                              void* d_out, int out_size, void* d_ws, size_t ws_size,
                              hipStream_t stream) {
    const float* x0    = (const float*)d_in[0];
    const int*   edge  = (const int*)d_in[1];
    const int*   batch = (const int*)d_in[2];
    const float* W     = (const float*)d_in[3];
    const float* bias  = (const float*)d_in[4];
    const float* lin_w = (const float*)d_in[5];
    const float* l1_w  = (const float*)d_in[6];
    const float* l1_b  = (const float*)d_in[7];
    const float* l2_w  = (const float*)d_in[8];
    const float* l2_b  = (const float*)d_in[9];
    float* out = (float*)d_out;

    int N = in_sizes[0] / H;
    int E = in_sizes[1] / 2;
    const int* src = edge;
    const int* dst = edge + E;

    size_t nh = (size_t)N * H;
    float* xA      = (float*)d_ws;
    float* xB      = xA + nh;
    half_t* xhA    = (half_t*)(xB + nh);
    half_t* xhB    = xhA + nh;
    half_t* WtTf   = xhB + nh;                // 32768 halfs
    int* deg       = (int*)(WtTf + 32768);
    int* row_start = deg + N;                 // N+1
    int* cursor    = row_start + N + 1;
    int* csr_src   = cursor + N;              // E
    int* partials  = csr_src + E;             // 64
    int* blkoff    = partials + 64;           // 64

    prep_kernel<<<128, 256, 0, stream>>>(W, lin_w, WtTf);
    cast_kernel<<<((int)(nh / 4) + 255) / 256, 256, 0, stream>>>(x0, xhA, (int)(nh / 4));

    hipMemsetAsync(deg, 0, (size_t)N * sizeof(int), stream);
    count_kernel<<<(E + 255) / 256, 256, 0, stream>>>(dst, deg, E);
    int nblk = (N + SCHUNK - 1) / SCHUNK;
    scan_part<<<nblk, 256, 0, stream>>>(deg, partials, N);
    scan_mid<<<1, 64, 0, stream>>>(partials, blkoff, nblk);
    scan_final<<<nblk, 256, 0, stream>>>(deg, blkoff, row_start, cursor, N, E);
    fill_kernel<<<(E + 255) / 256, 256, 0, stream>>>(src, dst, cursor, csr_src, E);

    const float* xcur = x0;
    const half_t* xcur_h = xhA;
    int nblocks = (N + CROWS - 1) / CROWS;
    for (int it = 0; it < 5; ++it) {
        float* xnext = (it & 1) ? xB : xA;
        half_t* xnext_h = (it & 1) ? xhA : xhB;
        fused_iter<<<nblocks, 256, 0, stream>>>(
            xcur, xcur_h, row_start, csr_src, WtTf, bias, xnext, xnext_h, N, it < 4 ? 1 : 0);
        xcur = xnext;
        xcur_h = xnext_h;
    }

    pool_mlp<<<NGRAPH, 1024, 0, stream>>>(xcur, batch, l1_w, l1_b, l2_w, l2_b, out, N);
}

// Round 9
// 396.764 us; speedup vs baseline: 1.6636x; 1.6636x over previous
//
#include <hip/hip_runtime.h>
#include <hip/hip_fp16.h>
#include <cmath>

#define H 128
#define GAMMA 0.1f
#define EPS 0.1f
#define NEG 0.01f
#define NGRAPH 256

typedef _Float16 half_t;
typedef _Float16 f16x8 __attribute__((ext_vector_type(8)));
typedef _Float16 f16x4 __attribute__((ext_vector_type(4)));
typedef float f32x4 __attribute__((ext_vector_type(4)));

__device__ __forceinline__ float fast_tanh(float v) {
    float e = __builtin_amdgcn_exp2f(v * 2.8853900817779268f);
    float r = __builtin_amdgcn_rcpf(e + 1.0f);
    return 1.0f - 2.0f * r;
}

// ---------------- precompute weights in MFMA B-fragment order:
// WtTf[((s*8+ct)*64+lane)*8+t] = M[j=ct*16+(lane&15)][k=s*32+(lane>>4)*8+t]
// M[j][k] = (k<H) ? W[j][k]-W[k][j]-gamma*delta(j,k) : lin_w[j][k-H]
__global__ void prep_kernel(const float* __restrict__ W, const float* __restrict__ lin_w,
                            half_t* __restrict__ WtTf) {
    int idx = blockIdx.x * 256 + threadIdx.x;   // 32768 threads
    int t = idx & 7;
    int lane = (idx >> 3) & 63;
    int ct = (idx >> 9) & 7;
    int s = idx >> 12;
    int q = lane >> 4, m = lane & 15;
    int j = ct * 16 + m;
    int k = s * 32 + q * 8 + t;
    float v;
    if (k < H) v = W[j * H + k] - W[k * H + j] - (j == k ? GAMMA : 0.f);
    else       v = lin_w[j * H + (k - H)];
    WtTf[idx] = (half_t)v;
}

// ---------------- f32 -> f16 cast (x0 -> xh)
__global__ void cast_kernel(const float* __restrict__ x, half_t* __restrict__ xh, int n4) {
    int i = blockIdx.x * 256 + threadIdx.x;
    if (i < n4) {
        float4 v = *(const float4*)(x + (size_t)i * 4);
        half_t* o = xh + (size_t)i * 4;
        o[0] = (half_t)v.x; o[1] = (half_t)v.y; o[2] = (half_t)v.z; o[3] = (half_t)v.w;
    }
}

// ---------------- CSR build
__global__ void count_kernel(const int* __restrict__ dst, int* __restrict__ deg, int E) {
    int e = blockIdx.x * blockDim.x + threadIdx.x;
    if (e < E) atomicAdd(&deg[dst[e]], 1);
}

#define SCHUNK 2048
__global__ __launch_bounds__(256) void scan_part(const int* __restrict__ deg,
                                                 int* __restrict__ partials, int N) {
    __shared__ int red[256];
    int t = threadIdx.x, b = blockIdx.x;
    int base = b * SCHUNK + t * 8;
    int s = 0;
#pragma unroll
    for (int i = 0; i < 8; ++i) { int idx = base + i; if (idx < N) s += deg[idx]; }
    red[t] = s;
    __syncthreads();
    for (int off = 128; off > 0; off >>= 1) {
        if (t < off) red[t] += red[t + off];
        __syncthreads();
    }
    if (t == 0) partials[b] = red[0];
}

__global__ void scan_mid(const int* __restrict__ partials, int* __restrict__ blkoff, int nblk) {
    int lane = threadIdx.x;   // 64 threads
    int p = (lane < nblk) ? partials[lane] : 0;
    int v = p;
    for (int off = 1; off < 64; off <<= 1) {
        int u = __shfl_up(v, off);
        if (lane >= off) v += u;
    }
    if (lane < nblk) blkoff[lane] = v - p;
}

__global__ __launch_bounds__(256) void scan_final(const int* __restrict__ deg,
        const int* __restrict__ blkoff, int* __restrict__ row_start,
        int* __restrict__ cursor, int N, int E) {
    __shared__ int red[256];
    int t = threadIdx.x, b = blockIdx.x;
    int base = b * SCHUNK + t * 8;
    int v[8]; int s = 0;
#pragma unroll
    for (int i = 0; i < 8; ++i) { int idx = base + i; v[i] = (idx < N) ? deg[idx] : 0; s += v[i]; }
    red[t] = s;
    __syncthreads();
    for (int off = 1; off < 256; off <<= 1) {
        int u = (t >= off) ? red[t - off] : 0;
        __syncthreads();
        red[t] += u;
        __syncthreads();
    }
    int run = blkoff[b] + red[t] - s;
#pragma unroll
    for (int i = 0; i < 8; ++i) {
        int idx = base + i;
        if (idx < N) { row_start[idx] = run; cursor[idx] = run; run += v[i]; }
    }
    if (b == 0 && t == 0) row_start[N] = E;
}

__global__ void fill_kernel(const int* __restrict__ src, const int* __restrict__ dst,
                            int* __restrict__ cursor, int* __restrict__ csr_src, int E) {
    int e = blockIdx.x * blockDim.x + threadIdx.x;
    if (e < E) {
        int p = atomicAdd(&cursor[dst[e]], 1);
        csr_src[p] = src[e];
    }
}

// ---------------- gather aggregation (R4-proven): one wave per dst node.
// lane = 32*half + li ; lane covers features [4*li, 4*li+4) (f16x4 = 8B).
// half 0 takes even edges, half 1 odd edges; combined via shfl_xor(32).
// Exec-mask discipline: every __shfl executes with the full wave active.
__global__ __launch_bounds__(256) void gather_agg(const half_t* __restrict__ xh,
        const int* __restrict__ row_start, const int* __restrict__ csr_src,
        half_t* __restrict__ xaggh, int N) {
    int node = blockIdx.x * 4 + (threadIdx.x >> 6);
    if (node >= N) return;
    int lane = threadIdx.x & 63;
    int half = lane >> 5, li = lane & 31;
    int begin = row_start[node], end = row_start[node + 1];
    float a0 = 0.f, a1 = 0.f, a2 = 0.f, a3 = 0.f;
    float b0 = 0.f, b1 = 0.f, b2 = 0.f, b3 = 0.f;
    for (int base = begin; base < end; base += 64) {
        int cnt = min(64, end - base);
        int myidx = (lane < cnt) ? csr_src[base + lane] : 0;
        int j = 0;
        for (; j + 3 < cnt; j += 4) {
            int s0 = __shfl(myidx, j + half);
            int s1 = __shfl(myidx, j + 2 + half);
            f16x4 v0 = *(const f16x4*)(xh + (size_t)s0 * H + li * 4);
            f16x4 v1 = *(const f16x4*)(xh + (size_t)s1 * H + li * 4);
            a0 += (float)v0[0]; a1 += (float)v0[1]; a2 += (float)v0[2]; a3 += (float)v0[3];
            b0 += (float)v1[0]; b1 += (float)v1[1]; b2 += (float)v1[2]; b3 += (float)v1[3];
        }
        for (; j < cnt; j += 2) {
            // uniform: all lanes shfl; only valid halves accumulate
            int sel = (j + half < cnt) ? (j + half) : j;
            int s0 = __shfl(myidx, sel);
            f16x4 v0 = *(const f16x4*)(xh + (size_t)s0 * H + li * 4);
            if (j + half < cnt) {
                a0 += (float)v0[0]; a1 += (float)v0[1]; a2 += (float)v0[2]; a3 += (float)v0[3];
            }
        }
    }
    a0 += b0; a1 += b1; a2 += b2; a3 += b3;
    a0 += __shfl_xor(a0, 32); a1 += __shfl_xor(a1, 32);
    a2 += __shfl_xor(a2, 32); a3 += __shfl_xor(a3, 32);
    if (half == 0) {
        f16x4 o; o[0] = (half_t)a0; o[1] = (half_t)a1; o[2] = (half_t)a2; o[3] = (half_t)a3;
        *(f16x4*)(xaggh + (size_t)node * H + li * 4) = o;
    }
}

// ---------------- conv+update via f16 MFMA, f16-only state.
// xh_out = xh + EPS*tanh( [xh | xagg] @ M^T + bias ) ; all operands f16 in HBM,
// residual+tanh in f32. B-fragments read coalesced from fragment-ordered WtTf
// (64 KB, L2-hot) -> no LDS at all.
#define CROWS 128
__global__ __launch_bounds__(256) void conv_mfma(
        const half_t* __restrict__ xh, const half_t* __restrict__ xaggh,
        const half_t* __restrict__ WtTf, const float* __restrict__ bias,
        half_t* __restrict__ xhout, int N) {
    int tid = threadIdx.x;
    int wave = tid >> 6, lane = tid & 63;
    int q = lane >> 4, m = lane & 15;
    int n0 = blockIdx.x * CROWS + wave * 32;

    f32x4 acc[2][8];
#pragma unroll
    for (int rt = 0; rt < 2; ++rt)
#pragma unroll
        for (int ct = 0; ct < 8; ++ct) acc[rt][ct] = (f32x4){0.f, 0.f, 0.f, 0.f};

#pragma unroll
    for (int s = 0; s < 8; ++s) {
        f16x8 afrag[2];
#pragma unroll
        for (int rt = 0; rt < 2; ++rt) {
            int row = min(n0 + rt * 16 + m, N - 1);
            afrag[rt] = (s < 4)
                ? *(const f16x8*)(xh    + (size_t)row * H + s * 32 + q * 8)
                : *(const f16x8*)(xaggh + (size_t)row * H + (s - 4) * 32 + q * 8);
        }
#pragma unroll
        for (int ct = 0; ct < 8; ++ct) {
            f16x8 bfrag = *(const f16x8*)(WtTf + ((s * 8 + ct) * 64 + lane) * 8);
            acc[0][ct] = __builtin_amdgcn_mfma_f32_16x16x32_f16(afrag[0], bfrag, acc[0][ct], 0, 0, 0);
            acc[1][ct] = __builtin_amdgcn_mfma_f32_16x16x32_f16(afrag[1], bfrag, acc[1][ct], 0, 0, 0);
        }
    }

#pragma unroll
    for (int rt = 0; rt < 2; ++rt) {
#pragma unroll
        for (int r = 0; r < 4; ++r) {
            int row = n0 + rt * 16 + q * 4 + r;
            if (row < N) {
#pragma unroll
                for (int ct = 0; ct < 8; ++ct) {
                    int col = ct * 16 + m;
                    float c = acc[rt][ct][r] + bias[col];
                    float o = (float)xh[(size_t)row * H + col] + EPS * fast_tanh(c);
                    xhout[(size_t)row * H + col] = (half_t)o;
                }
            }
        }
    }
}

// ---------------- fused triple pooling + 2-layer MLP (one block per graph)
__global__ __launch_bounds__(1024) void pool_mlp(const half_t* __restrict__ x,
        const int* __restrict__ batch,
        const float* __restrict__ l1_w, const float* __restrict__ l1_b,
        const float* __restrict__ l2_w, const float* __restrict__ l2_b,
        float* __restrict__ out, int N) {
    __shared__ float ssum[8][128];
    __shared__ float smax[8][128];
    __shared__ __align__(16) float sp[384];
    __shared__ __align__(16) float sh[192];
    int g = blockIdx.x, t = threadIdx.x;
    int feat = t & 127, slot = t >> 7;   // 8 slots
    int lo = 0, hi = N;
    while (lo < hi) { int mid = (lo + hi) >> 1; if (batch[mid] < g) lo = mid + 1; else hi = mid; }
    int start = lo;
    hi = N;
    while (lo < hi) { int mid = (lo + hi) >> 1; if (batch[mid] < g + 1) lo = mid + 1; else hi = mid; }
    int end = lo;
    float sum = 0.f, mx = -INFINITY;
    for (int n = start + slot; n < end; n += 8) {
        float v = (float)x[(size_t)n * H + feat];
        sum += v;
        mx = fmaxf(mx, v);
    }
    ssum[slot][feat] = sum;
    smax[slot][feat] = mx;
    __syncthreads();
    if (t < 128) {
        float s = 0.f, m = -INFINITY;
#pragma unroll
        for (int k = 0; k < 8; ++k) { s += ssum[k][t]; m = fmaxf(m, smax[k][t]); }
        int cnt = end - start;
        sp[t] = s;
        sp[128 + t] = (cnt > 0) ? m : 0.f;
        sp[256 + t] = s / (float)(cnt > 0 ? cnt : 1);
    }
    __syncthreads();
    if (t < 192) {
        float acc = l1_b[t];
        const float* wr = l1_w + (size_t)t * 384;
        for (int k = 0; k < 384; k += 4) {
            float4 w = *(const float4*)(wr + k);
            float4 p = *(const float4*)(sp + k);
            acc += w.x * p.x + w.y * p.y + w.z * p.z + w.w * p.w;
        }
        sh[t] = acc > 0.f ? acc : NEG * acc;
    }
    __syncthreads();
    if (t < 64) {
        float acc = l2_b[t];
        const float* wr = l2_w + (size_t)t * 192;
        for (int k = 0; k < 192; k += 4) {
            float4 w = *(const float4*)(wr + k);
            float4 p = *(const float4*)(sh + k);
            acc += w.x * p.x + w.y * p.y + w.z * p.z + w.w * p.w;
        }
        out[g * 64 + t] = acc > 0.f ? acc : NEG * acc;
    }
}

extern "C" void kernel_launch(void* const* d_in, const int* in_sizes, int n_in,
                              void* d_out, int out_size, void* d_ws, size_t ws_size,
                              hipStream_t stream) {
    const float* x0    = (const float*)d_in[0];
    const int*   edge  = (const int*)d_in[1];
    const int*   batch = (const int*)d_in[2];
    const float* W     = (const float*)d_in[3];
    const float* bias  = (const float*)d_in[4];
    const float* lin_w = (const float*)d_in[5];
    const float* l1_w  = (const float*)d_in[6];
    const float* l1_b  = (const float*)d_in[7];
    const float* l2_w  = (const float*)d_in[8];
    const float* l2_b  = (const float*)d_in[9];
    float* out = (float*)d_out;

    int N = in_sizes[0] / H;
    int E = in_sizes[1] / 2;
    const int* src = edge;
    const int* dst = edge + E;

    size_t nh = (size_t)N * H;
    half_t* xhA    = (half_t*)d_ws;
    half_t* xhB    = xhA + nh;
    half_t* xaggh  = xhB + nh;
    half_t* WtTf   = xaggh + nh;              // 32768 halfs
    int* deg       = (int*)(WtTf + 32768);
    int* row_start = deg + N;                 // N+1
    int* cursor    = row_start + N + 1;
    int* csr_src   = cursor + N;              // E
    int* partials  = csr_src + E;             // 64
    int* blkoff    = partials + 64;           // 64

    prep_kernel<<<128, 256, 0, stream>>>(W, lin_w, WtTf);
    cast_kernel<<<((int)(nh / 4) + 255) / 256, 256, 0, stream>>>(x0, xhA, (int)(nh / 4));

    hipMemsetAsync(deg, 0, (size_t)N * sizeof(int), stream);
    count_kernel<<<(E + 255) / 256, 256, 0, stream>>>(dst, deg, E);
    int nblk = (N + SCHUNK - 1) / SCHUNK;
    scan_part<<<nblk, 256, 0, stream>>>(deg, partials, N);
    scan_mid<<<1, 64, 0, stream>>>(partials, blkoff, nblk);
    scan_final<<<nblk, 256, 0, stream>>>(deg, blkoff, row_start, cursor, N, E);
    fill_kernel<<<(E + 255) / 256, 256, 0, stream>>>(src, dst, cursor, csr_src, E);

    const half_t* xcur_h = xhA;
    int nblocks = (N + CROWS - 1) / CROWS;
    for (int it = 0; it < 5; ++it) {
        gather_agg<<<(N + 3) / 4, 256, 0, stream>>>(xcur_h, row_start, csr_src, xaggh, N);
        half_t* xnext_h = (it & 1) ? xhA : xhB;
        conv_mfma<<<nblocks, 256, 0, stream>>>(xcur_h, xaggh, WtTf, bias, xnext_h, N);
        xcur_h = xnext_h;
    }

    pool_mlp<<<NGRAPH, 1024, 0, stream>>>(xcur_h, batch, l1_w, l1_b, l2_w, l2_b, out, N);
}

// Round 10
// 376.192 us; speedup vs baseline: 1.7545x; 1.0547x over previous
//
#include <hip/hip_runtime.h>
#include <hip/hip_fp16.h>
#include <cmath>

#define H 128
#define GAMMA 0.1f
#define EPS 0.1f
#define NEG 0.01f
#define NGRAPH 256

typedef _Float16 half_t;
typedef _Float16 f16x8 __attribute__((ext_vector_type(8)));
typedef _Float16 f16x4 __attribute__((ext_vector_type(4)));
typedef _Float16 f16x2 __attribute__((ext_vector_type(2)));
typedef float f32x4 __attribute__((ext_vector_type(4)));

__device__ __forceinline__ float fast_tanh(float v) {
    float e = __builtin_amdgcn_exp2f(v * 2.8853900817779268f);
    float r = __builtin_amdgcn_rcpf(e + 1.0f);
    return 1.0f - 2.0f * r;
}

// ---------------- precompute weights in MFMA B-fragment order:
// WtTf[((s*8+ct)*64+lane)*8+t] = M[j=ct*16+(lane&15)][k=s*32+(lane>>4)*8+t]
// M[j][k] = (k<H) ? W[j][k]-W[k][j]-gamma*delta(j,k) : lin_w[j][k-H]
__global__ void prep_kernel(const float* __restrict__ W, const float* __restrict__ lin_w,
                            half_t* __restrict__ WtTf) {
    int idx = blockIdx.x * 256 + threadIdx.x;   // 32768 threads
    int t = idx & 7;
    int lane = (idx >> 3) & 63;
    int ct = (idx >> 9) & 7;
    int s = idx >> 12;
    int q = lane >> 4, m = lane & 15;
    int j = ct * 16 + m;
    int k = s * 32 + q * 8 + t;
    float v;
    if (k < H) v = W[j * H + k] - W[k * H + j] - (j == k ? GAMMA : 0.f);
    else       v = lin_w[j * H + (k - H)];
    WtTf[idx] = (half_t)v;
}

// ---------------- f32 -> f16 cast (x0 -> xh)
__global__ void cast_kernel(const float* __restrict__ x, half_t* __restrict__ xh, int n4) {
    int i = blockIdx.x * 256 + threadIdx.x;
    if (i < n4) {
        float4 v = *(const float4*)(x + (size_t)i * 4);
        half_t* o = xh + (size_t)i * 4;
        o[0] = (half_t)v.x; o[1] = (half_t)v.y; o[2] = (half_t)v.z; o[3] = (half_t)v.w;
    }
}

// ---------------- CSR build
__global__ void count_kernel(const int* __restrict__ dst, int* __restrict__ deg, int E) {
    int e = blockIdx.x * blockDim.x + threadIdx.x;
    if (e < E) atomicAdd(&deg[dst[e]], 1);
}

#define SCHUNK 2048
__global__ __launch_bounds__(256) void scan_part(const int* __restrict__ deg,
                                                 int* __restrict__ partials, int N) {
    __shared__ int red[256];
    int t = threadIdx.x, b = blockIdx.x;
    int base = b * SCHUNK + t * 8;
    int s = 0;
#pragma unroll
    for (int i = 0; i < 8; ++i) { int idx = base + i; if (idx < N) s += deg[idx]; }
    red[t] = s;
    __syncthreads();
    for (int off = 128; off > 0; off >>= 1) {
        if (t < off) red[t] += red[t + off];
        __syncthreads();
    }
    if (t == 0) partials[b] = red[0];
}

__global__ void scan_mid(const int* __restrict__ partials, int* __restrict__ blkoff, int nblk) {
    int lane = threadIdx.x;   // 64 threads
    int p = (lane < nblk) ? partials[lane] : 0;
    int v = p;
    for (int off = 1; off < 64; off <<= 1) {
        int u = __shfl_up(v, off);
        if (lane >= off) v += u;
    }
    if (lane < nblk) blkoff[lane] = v - p;
}

__global__ __launch_bounds__(256) void scan_final(const int* __restrict__ deg,
        const int* __restrict__ blkoff, int* __restrict__ row_start,
        int* __restrict__ cursor, int N, int E) {
    __shared__ int red[256];
    int t = threadIdx.x, b = blockIdx.x;
    int base = b * SCHUNK + t * 8;
    int v[8]; int s = 0;
#pragma unroll
    for (int i = 0; i < 8; ++i) { int idx = base + i; v[i] = (idx < N) ? deg[idx] : 0; s += v[i]; }
    red[t] = s;
    __syncthreads();
    for (int off = 1; off < 256; off <<= 1) {
        int u = (t >= off) ? red[t - off] : 0;
        __syncthreads();
        red[t] += u;
        __syncthreads();
    }
    int run = blkoff[b] + red[t] - s;
#pragma unroll
    for (int i = 0; i < 8; ++i) {
        int idx = base + i;
        if (idx < N) { row_start[idx] = run; cursor[idx] = run; run += v[i]; }
    }
    if (b == 0 && t == 0) row_start[N] = E;
}

__global__ void fill_kernel(const int* __restrict__ src, const int* __restrict__ dst,
                            int* __restrict__ cursor, int* __restrict__ csr_src, int E) {
    int e = blockIdx.x * blockDim.x + threadIdx.x;
    if (e < E) {
        int p = atomicAdd(&cursor[dst[e]], 1);
        csr_src[p] = src[e];
    }
}

// ---------------- gather aggregation v3: one wave per dst node, scalar-uniform
// control. wave id forced uniform via readfirstlane -> begin/end in SGPRs.
// Edge indices: one vector load per 64-edge chunk, then v_readlane (dynamic
// uniform lane, cheap VALU) per edge -> row base in SGPR, NO ds_bpermute.
// Lane covers features [2*lane, 2*lane+1] (f16x2, 4B) -> no cross-lane
// reduction. 8 edges/step = 8 independent loads in flight; masked 7-wide tail.
__global__ __launch_bounds__(256) void gather_agg(const half_t* __restrict__ xh,
        const int* __restrict__ row_start, const int* __restrict__ csr_src,
        half_t* __restrict__ xaggh, int N) {
    int wave = __builtin_amdgcn_readfirstlane(threadIdx.x >> 6);
    int node = blockIdx.x * 4 + wave;
    if (node >= N) return;                       // wave-uniform
    int lane = threadIdx.x & 63;
    int begin = row_start[node];                 // uniform -> scalar
    int end   = row_start[node + 1];
    float a0 = 0.f, a1 = 0.f;
    for (int base = begin; base < end; base += 64) {
        int cnt = min(64, end - base);           // uniform, >=1
        int myidx = csr_src[base + min(lane, cnt - 1)];
        int j = 0;
        for (; j + 7 < cnt; j += 8) {            // 8 loads in flight
            int s0 = __builtin_amdgcn_readlane(myidx, j + 0);
            int s1 = __builtin_amdgcn_readlane(myidx, j + 1);
            int s2 = __builtin_amdgcn_readlane(myidx, j + 2);
            int s3 = __builtin_amdgcn_readlane(myidx, j + 3);
            int s4 = __builtin_amdgcn_readlane(myidx, j + 4);
            int s5 = __builtin_amdgcn_readlane(myidx, j + 5);
            int s6 = __builtin_amdgcn_readlane(myidx, j + 6);
            int s7 = __builtin_amdgcn_readlane(myidx, j + 7);
            f16x2 v0 = *(const f16x2*)(xh + (size_t)s0 * H + lane * 2);
            f16x2 v1 = *(const f16x2*)(xh + (size_t)s1 * H + lane * 2);
            f16x2 v2 = *(const f16x2*)(xh + (size_t)s2 * H + lane * 2);
            f16x2 v3 = *(const f16x2*)(xh + (size_t)s3 * H + lane * 2);
            f16x2 v4 = *(const f16x2*)(xh + (size_t)s4 * H + lane * 2);
            f16x2 v5 = *(const f16x2*)(xh + (size_t)s5 * H + lane * 2);
            f16x2 v6 = *(const f16x2*)(xh + (size_t)s6 * H + lane * 2);
            f16x2 v7 = *(const f16x2*)(xh + (size_t)s7 * H + lane * 2);
            a0 += (float)v0[0] + (float)v1[0] + (float)v2[0] + (float)v3[0]
                + (float)v4[0] + (float)v5[0] + (float)v6[0] + (float)v7[0];
            a1 += (float)v0[1] + (float)v1[1] + (float)v2[1] + (float)v3[1]
                + (float)v4[1] + (float)v5[1] + (float)v6[1] + (float)v7[1];
        }
        if (j < cnt) {                           // masked 7-wide tail, uniform
            int rem = cnt - j;                   // 1..7
#pragma unroll
            for (int k = 0; k < 7; ++k) {
                int sel = j + (k < rem ? k : 0); // clamped dup -> L1 hit
                int sk = __builtin_amdgcn_readlane(myidx, sel);
                f16x2 vk = *(const f16x2*)(xh + (size_t)sk * H + lane * 2);
                float w = (k < rem) ? 1.f : 0.f;
                a0 += w * (float)vk[0];
                a1 += w * (float)vk[1];
            }
        }
    }
    f16x2 o; o[0] = (half_t)a0; o[1] = (half_t)a1;
    *(f16x2*)(xaggh + (size_t)node * H + lane * 2) = o;
}

// ---------------- conv+update via f16 MFMA, f16-only state.
// xh_out = xh + EPS*tanh( [xh | xagg] @ M^T + bias ). B-fragments read
// coalesced from fragment-ordered WtTf (64 KB, L2-hot) -> no LDS at all.
#define CROWS 128
__global__ __launch_bounds__(256) void conv_mfma(
        const half_t* __restrict__ xh, const half_t* __restrict__ xaggh,
        const half_t* __restrict__ WtTf, const float* __restrict__ bias,
        half_t* __restrict__ xhout, int N) {
    int tid = threadIdx.x;
    int wave = tid >> 6, lane = tid & 63;
    int q = lane >> 4, m = lane & 15;
    int n0 = blockIdx.x * CROWS + wave * 32;

    f32x4 acc[2][8];
#pragma unroll
    for (int rt = 0; rt < 2; ++rt)
#pragma unroll
        for (int ct = 0; ct < 8; ++ct) acc[rt][ct] = (f32x4){0.f, 0.f, 0.f, 0.f};

#pragma unroll
    for (int s = 0; s < 8; ++s) {
        f16x8 afrag[2];
#pragma unroll
        for (int rt = 0; rt < 2; ++rt) {
            int row = min(n0 + rt * 16 + m, N - 1);
            afrag[rt] = (s < 4)
                ? *(const f16x8*)(xh    + (size_t)row * H + s * 32 + q * 8)
                : *(const f16x8*)(xaggh + (size_t)row * H + (s - 4) * 32 + q * 8);
        }
#pragma unroll
        for (int ct = 0; ct < 8; ++ct) {
            f16x8 bfrag = *(const f16x8*)(WtTf + ((s * 8 + ct) * 64 + lane) * 8);
            acc[0][ct] = __builtin_amdgcn_mfma_f32_16x16x32_f16(afrag[0], bfrag, acc[0][ct], 0, 0, 0);
            acc[1][ct] = __builtin_amdgcn_mfma_f32_16x16x32_f16(afrag[1], bfrag, acc[1][ct], 0, 0, 0);
        }
    }

#pragma unroll
    for (int rt = 0; rt < 2; ++rt) {
#pragma unroll
        for (int r = 0; r < 4; ++r) {
            int row = n0 + rt * 16 + q * 4 + r;
            if (row < N) {
#pragma unroll
                for (int ct = 0; ct < 8; ++ct) {
                    int col = ct * 16 + m;
                    float c = acc[rt][ct][r] + bias[col];
                    float o = (float)xh[(size_t)row * H + col] + EPS * fast_tanh(c);
                    xhout[(size_t)row * H + col] = (half_t)o;
                }
            }
        }
    }
}

// ---------------- fused triple pooling + 2-layer MLP (one block per graph)
__global__ __launch_bounds__(1024) void pool_mlp(const half_t* __restrict__ x,
        const int* __restrict__ batch,
        const float* __restrict__ l1_w, const float* __restrict__ l1_b,
        const float* __restrict__ l2_w, const float* __restrict__ l2_b,
        float* __restrict__ out, int N) {
    __shared__ float ssum[8][128];
    __shared__ float smax[8][128];
    __shared__ __align__(16) float sp[384];
    __shared__ __align__(16) float sh[192];
    int g = blockIdx.x, t = threadIdx.x;
    int feat = t & 127, slot = t >> 7;   // 8 slots
    int lo = 0, hi = N;
    while (lo < hi) { int mid = (lo + hi) >> 1; if (batch[mid] < g) lo = mid + 1; else hi = mid; }
    int start = lo;
    hi = N;
    while (lo < hi) { int mid = (lo + hi) >> 1; if (batch[mid] < g + 1) lo = mid + 1; else hi = mid; }
    int end = lo;
    float sum = 0.f, mx = -INFINITY;
    for (int n = start + slot; n < end; n += 8) {
        float v = (float)x[(size_t)n * H + feat];
        sum += v;
        mx = fmaxf(mx, v);
    }
    ssum[slot][feat] = sum;
    smax[slot][feat] = mx;
    __syncthreads();
    if (t < 128) {
        float s = 0.f, m = -INFINITY;
#pragma unroll
        for (int k = 0; k < 8; ++k) { s += ssum[k][t]; m = fmaxf(m, smax[k][t]); }
        int cnt = end - start;
        sp[t] = s;
        sp[128 + t] = (cnt > 0) ? m : 0.f;
        sp[256 + t] = s / (float)(cnt > 0 ? cnt : 1);
    }
    __syncthreads();
    if (t < 192) {
        float acc = l1_b[t];
        const float* wr = l1_w + (size_t)t * 384;
        for (int k = 0; k < 384; k += 4) {
            float4 w = *(const float4*)(wr + k);
            float4 p = *(const float4*)(sp + k);
            acc += w.x * p.x + w.y * p.y + w.z * p.z + w.w * p.w;
        }
        sh[t] = acc > 0.f ? acc : NEG * acc;
    }
    __syncthreads();
    if (t < 64) {
        float acc = l2_b[t];
        const float* wr = l2_w + (size_t)t * 192;
        for (int k = 0; k < 192; k += 4) {
            float4 w = *(const float4*)(wr + k);
            float4 p = *(const float4*)(sh + k);
            acc += w.x * p.x + w.y * p.y + w.z * p.z + w.w * p.w;
        }
        out[g * 64 + t] = acc > 0.f ? acc : NEG * acc;
    }
}

extern "C" void kernel_launch(void* const* d_in, const int* in_sizes, int n_in,
                              void* d_out, int out_size, void* d_ws, size_t ws_size,
                              hipStream_t stream) {
    const float* x0    = (const float*)d_in[0];
    const int*   edge  = (const int*)d_in[1];
    const int*   batch = (const int*)d_in[2];
    const float* W     = (const float*)d_in[3];
    const float* bias  = (const float*)d_in[4];
    const float* lin_w = (const float*)d_in[5];
    const float* l1_w  = (const float*)d_in[6];
    const float* l1_b  = (const float*)d_in[7];
    const float* l2_w  = (const float*)d_in[8];
    const float* l2_b  = (const float*)d_in[9];
    float* out = (float*)d_out;

    int N = in_sizes[0] / H;
    int E = in_sizes[1] / 2;
    const int* src = edge;
    const int* dst = edge + E;

    size_t nh = (size_t)N * H;
    half_t* xhA    = (half_t*)d_ws;
    half_t* xhB    = xhA + nh;
    half_t* xaggh  = xhB + nh;
    half_t* WtTf   = xaggh + nh;              // 32768 halfs
    int* deg       = (int*)(WtTf + 32768);
    int* row_start = deg + N;                 // N+1
    int* cursor    = row_start + N + 1;
    int* csr_src   = cursor + N;              // E
    int* partials  = csr_src + E;             // 64
    int* blkoff    = partials + 64;           // 64

    prep_kernel<<<128, 256, 0, stream>>>(W, lin_w, WtTf);
    cast_kernel<<<((int)(nh / 4) + 255) / 256, 256, 0, stream>>>(x0, xhA, (int)(nh / 4));

    hipMemsetAsync(deg, 0, (size_t)N * sizeof(int), stream);
    count_kernel<<<(E + 255) / 256, 256, 0, stream>>>(dst, deg, E);
    int nblk = (N + SCHUNK - 1) / SCHUNK;
    scan_part<<<nblk, 256, 0, stream>>>(deg, partials, N);
    scan_mid<<<1, 64, 0, stream>>>(partials, blkoff, nblk);
    scan_final<<<nblk, 256, 0, stream>>>(deg, blkoff, row_start, cursor, N, E);
    fill_kernel<<<(E + 255) / 256, 256, 0, stream>>>(src, dst, cursor, csr_src, E);

    const half_t* xcur_h = xhA;
    int nblocks = (N + CROWS - 1) / CROWS;
    for (int it = 0; it < 5; ++it) {
        gather_agg<<<(N + 3) / 4, 256, 0, stream>>>(xcur_h, row_start, csr_src, xaggh, N);
        half_t* xnext_h = (it & 1) ? xhA : xhB;
        conv_mfma<<<nblocks, 256, 0, stream>>>(xcur_h, xaggh, WtTf, bias, xnext_h, N);
        xcur_h = xnext_h;
    }

    pool_mlp<<<NGRAPH, 1024, 0, stream>>>(xcur_h, batch, l1_w, l1_b, l2_w, l2_b, out, N);
}